// Round 1
// baseline (3170.764 us; speedup 1.0000x reference)
//
#include <hip/hip_runtime.h>

#define T_STEPS 10
#define NN 10000
#define EE 320000
#define CC 128
#define NC (NN*CC)   // 1,280,000 floats per node-matrix

__device__ __forceinline__ float sigmoidf_(float x){ return 1.f/(1.f+__expf(-x)); }
__device__ __forceinline__ float tanhf_(float x){
  x = fminf(15.f, fmaxf(-15.f, x));
  float e = __expf(2.f*x);
  return (e-1.f)/(e+1.f);
}

// ---------------- prep: effective weights + combined biases + h0=0 ----------
// Wbig (768x384): rows 0-383 = x-side [W0-W2; W1; 2W2] for gates z|r|h~,
//                 rows 384-767 = h-side same for z|r, zeros for h~ columns.
// Wr (384x128): same construction from Whh.
__global__ __launch_bounds__(256) void prep_kernel(
    const float* __restrict__ Wxz, const float* __restrict__ Whz,
    const float* __restrict__ Wxr, const float* __restrict__ Whr,
    const float* __restrict__ Wxh, const float* __restrict__ Whh,
    const float* __restrict__ bxz, const float* __restrict__ bhz,
    const float* __restrict__ bxr, const float* __restrict__ bhr,
    const float* __restrict__ bxh, const float* __restrict__ bhh,
    float* __restrict__ Wbig, float* __restrict__ Wr,
    float* __restrict__ bz, float* __restrict__ br, float* __restrict__ bht,
    float* __restrict__ h)
{
  int idx = blockIdx.x*256 + threadIdx.x;
  if (idx < NC) h[idx] = 0.f;
  if (idx < 768*384) {
    int k = idx/384, c = idx - k*384;
    int gate = c >> 7, cc = c & 127;
    int hside = (k >= 384);
    int kk = hside ? k - 384 : k;
    int blk = kk >> 7, row = kk & 127;
    const float* W = nullptr;
    if (!hside) W = (gate==0) ? Wxz : (gate==1) ? Wxr : Wxh;
    else if (gate==0) W = Whz; else if (gate==1) W = Whr;
    float v = 0.f;
    if (W) {
      int base = row*CC + cc;
      float w0 = W[base], w1 = W[CC*CC + base], w2 = W[2*CC*CC + base];
      v = (blk==0) ? (w0 - w2) : (blk==1) ? w1 : (2.f*w2);
    }
    Wbig[idx] = v;
  }
  int i2 = idx - 768*384;
  if (i2 >= 0 && i2 < 384*128) {
    int k = i2 >> 7, cc = i2 & 127;
    int blk = k >> 7, row = k & 127;
    int base = row*CC + cc;
    float w0 = Whh[base], w1 = Whh[CC*CC+base], w2 = Whh[2*CC*CC+base];
    Wr[i2] = (blk==0) ? (w0-w2) : (blk==1) ? w1 : (2.f*w2);
  }
  int i3 = idx - 768*384 - 384*128;
  if (i3 >= 0 && i3 < CC) {
    bz[i3]  = bxz[i3] + bhz[i3];
    br[i3]  = bxr[i3] + bhr[i3];
    bht[i3] = bxh[i3] + bhh[i3];
  }
}

// ---------------- per-step graph build ----------------
__global__ __launch_bounds__(256) void zero_kernel(int* __restrict__ p, int n){
  int i = blockIdx.x*256+threadIdx.x;
  if (i<n) p[i]=0;
}

__global__ __launch_bounds__(256) void count_kernel(const int* __restrict__ src, const int* __restrict__ dst,
                                                    int* __restrict__ deg, int* __restrict__ cnt){
  int e = blockIdx.x*256+threadIdx.x;
  if (e>=EE) return;
  int s = src[e], d = dst[e];
  if (s!=d){ atomicAdd(&deg[s],1); atomicAdd(&cnt[d],1); }
}

__global__ __launch_bounds__(256) void dinv_kernel(const int* __restrict__ deg, float* __restrict__ dinv){
  int i = blockIdx.x*256+threadIdx.x;
  if (i<NN){ int d=deg[i]; dinv[i] = d>0 ? rsqrtf((float)d) : 0.f; }
}

// exclusive prefix sum over cnt[NN] -> rowptr[NN+1], plus a scratch copy wo[NN]
__global__ __launch_bounds__(1024) void scan_kernel(const int* __restrict__ cnt, int* __restrict__ rowptr, int* __restrict__ wo){
  __shared__ int buf[1024];
  __shared__ int carry_s;
  int tid = threadIdx.x;
  if (tid==0) carry_s = 0;
  __syncthreads();
  for (int base=0; base<NN; base+=1024){
    int i = base+tid;
    int v = (i<NN) ? cnt[i] : 0;
    buf[tid] = v;
    __syncthreads();
    for (int off=1; off<1024; off<<=1){
      int t = (tid>=off) ? buf[tid-off] : 0;
      __syncthreads();
      buf[tid] += t;
      __syncthreads();
    }
    int incl = buf[tid];
    int carry = carry_s;
    if (i<NN){
      int excl = carry + incl - v;
      rowptr[i] = excl;
      wo[i] = excl;
      if (i==NN-1) rowptr[NN] = carry + incl;
    }
    __syncthreads();
    if (tid==1023) carry_s = carry + incl;
    __syncthreads();
  }
}

__global__ __launch_bounds__(256) void scatter_kernel(const int* __restrict__ src, const int* __restrict__ dst,
                                                      const float* __restrict__ dinv, int* __restrict__ wo,
                                                      int* __restrict__ colA, float* __restrict__ wvA){
  int e = blockIdx.x*256+threadIdx.x;
  if (e>=EE) return;
  int s=src[e], d=dst[e];
  if (s!=d){
    float w = -dinv[s]*dinv[d];
    int pos = atomicAdd(&wo[d],1);
    colA[pos]=s; wvA[pos]=w;
  }
}

// ---------------- CSR SpMM: out[d,:] = sum_e w[e] * in[src[e],:] -----------
// one wave per row; 64 lanes x float2 = 128 channels; blockIdx.y picks input.
__global__ __launch_bounds__(256) void spmm_kernel(const int* __restrict__ rowptr, const int* __restrict__ colA,
                                                   const float* __restrict__ wvA,
                                                   const float* __restrict__ in0, float* __restrict__ out0,
                                                   const float* __restrict__ in1, float* __restrict__ out1){
  int wave = threadIdx.x >> 6, lane = threadIdx.x & 63;
  int row = blockIdx.x*4 + wave;
  const float* __restrict__ in = blockIdx.y ? in1 : in0;
  float* __restrict__ out = blockIdx.y ? out1 : out0;
  if (row >= NN) return;
  int k0 = rowptr[row], k1 = rowptr[row+1];
  float ax=0.f, ay=0.f;
  #pragma unroll 4
  for (int k=k0;k<k1;k++){
    int s = colA[k];
    float w = wvA[k];
    const float2 v = *(const float2*)(in + s*CC + lane*2);
    ax = fmaf(w, v.x, ax);
    ay = fmaf(w, v.y, ay);
  }
  float2 r; r.x=ax; r.y=ay;
  *(float2*)(out + row*CC + lane*2) = r;
}

// ---------------- fp32 tiled GEMM, A = concat of NSEG (N x 128) buffers ----
// BM=BN=64, BK=16, 256 threads, 4x4 per thread.
// EPI 0: o0[r*NCOLS+c] = acc + b0[c]                     (final projection)
// EPI 1: c<128 -> z=sigmoid(acc+bz) ; c<256 -> hr=sigmoid(acc+br)*h ; else chx=acc
// EPI 2: h = z*h + (1-z)*tanh(acc + chx + bht)
template<int NSEG, int NCOLS, int EPI>
__global__ __launch_bounds__(256) void gemm_kernel(
    const float* __restrict__ A0, const float* __restrict__ A1, const float* __restrict__ A2,
    const float* __restrict__ A3, const float* __restrict__ A4, const float* __restrict__ A5,
    const float* __restrict__ B,
    const float* __restrict__ b0, const float* __restrict__ b1,
    const float* __restrict__ haux, const float* __restrict__ chx, const float* __restrict__ zbuf,
    float* __restrict__ o0, float* __restrict__ o1, float* __restrict__ o2)
{
  __shared__ float As[16][68];
  __shared__ float Bs[16][68];
  const float* segs[6] = {A0,A1,A2,A3,A4,A5};
  int tid = threadIdx.x;
  int m0 = blockIdx.x*64, n0 = blockIdx.y*64;
  int arow = tid & 63, akk = (tid>>6)<<2;
  int bkk = tid & 15, bcol = (tid>>4)<<2;
  int ty = tid >> 4, tx = tid & 15;
  float acc[4][4];
  #pragma unroll
  for (int i=0;i<4;i++){
    #pragma unroll
    for (int j=0;j<4;j++) acc[i][j]=0.f;
  }
  int grow_l = m0 + arow;
  #pragma unroll
  for (int seg=0; seg<NSEG; ++seg){
    const float* __restrict__ A = segs[seg];
    for (int kb=0; kb<128; kb+=16){
      float4 av = make_float4(0.f,0.f,0.f,0.f);
      if (grow_l < NN) av = *(const float4*)(A + grow_l*CC + kb + akk);
      float4 bv = *(const float4*)(B + (seg*128 + kb + bkk)*NCOLS + n0 + bcol);
      __syncthreads();
      As[akk+0][arow]=av.x; As[akk+1][arow]=av.y; As[akk+2][arow]=av.z; As[akk+3][arow]=av.w;
      *(float4*)(&Bs[bkk][bcol]) = bv;
      __syncthreads();
      #pragma unroll
      for (int kk=0;kk<16;kk++){
        float4 a = *(const float4*)(&As[kk][ty<<2]);
        float4 b = *(const float4*)(&Bs[kk][tx<<2]);
        acc[0][0]=fmaf(a.x,b.x,acc[0][0]); acc[0][1]=fmaf(a.x,b.y,acc[0][1]);
        acc[0][2]=fmaf(a.x,b.z,acc[0][2]); acc[0][3]=fmaf(a.x,b.w,acc[0][3]);
        acc[1][0]=fmaf(a.y,b.x,acc[1][0]); acc[1][1]=fmaf(a.y,b.y,acc[1][1]);
        acc[1][2]=fmaf(a.y,b.z,acc[1][2]); acc[1][3]=fmaf(a.y,b.w,acc[1][3]);
        acc[2][0]=fmaf(a.z,b.x,acc[2][0]); acc[2][1]=fmaf(a.z,b.y,acc[2][1]);
        acc[2][2]=fmaf(a.z,b.z,acc[2][2]); acc[2][3]=fmaf(a.z,b.w,acc[2][3]);
        acc[3][0]=fmaf(a.w,b.x,acc[3][0]); acc[3][1]=fmaf(a.w,b.y,acc[3][1]);
        acc[3][2]=fmaf(a.w,b.z,acc[3][2]); acc[3][3]=fmaf(a.w,b.w,acc[3][3]);
      }
    }
  }
  #pragma unroll
  for (int i=0;i<4;i++){
    int grow = m0 + (ty<<2) + i;
    if (grow >= NN) continue;
    #pragma unroll
    for (int j=0;j<4;j++){
      int gcol = n0 + (tx<<2) + j;
      float v = acc[i][j];
      if (EPI==0){
        o0[grow*NCOLS + gcol] = v + b0[gcol];
      } else if (EPI==1){
        if (gcol < 128){
          o0[grow*CC + gcol] = sigmoidf_(v + b0[gcol]);
        } else if (gcol < 256){
          int c = gcol - 128;
          float rr = sigmoidf_(v + b1[c]);
          o1[grow*CC + c] = rr * haux[grow*CC + c];
        } else {
          o2[grow*CC + (gcol-256)] = v;
        }
      } else {
        float pre = v + chx[grow*CC + gcol] + b0[gcol];
        float ht = tanhf_(pre);
        float zz = zbuf[grow*CC + gcol];
        float hv = haux[grow*CC + gcol];
        o0[grow*CC + gcol] = fmaf(zz, hv - ht, ht);  // z*h + (1-z)*ht
      }
    }
  }
}

extern "C" void kernel_launch(void* const* d_in, const int* in_sizes, int n_in,
                              void* d_out, int out_size, void* d_ws, size_t ws_size,
                              hipStream_t stream)
{
  (void)in_sizes; (void)n_in; (void)out_size; (void)ws_size;
  const float* feat = (const float*)d_in[0];
  const int*   edges = (const int*)d_in[1];
  const float* Wxz=(const float*)d_in[2];  const float* bxz=(const float*)d_in[3];
  const float* Whz=(const float*)d_in[4];  const float* bhz=(const float*)d_in[5];
  const float* Wxr=(const float*)d_in[6];  const float* bxr=(const float*)d_in[7];
  const float* Whr=(const float*)d_in[8];  const float* bhr=(const float*)d_in[9];
  const float* Wxh=(const float*)d_in[10]; const float* bxh=(const float*)d_in[11];
  const float* Whh=(const float*)d_in[12]; const float* bhh=(const float*)d_in[13];
  const float* Wp =(const float*)d_in[14]; const float* bp =(const float*)d_in[15];
  float* out = (float*)d_out;

  float* ws = (float*)d_ws;
  float* h     = ws;
  float* agg1x = ws + 1*(size_t)NC;
  float* agg2x = ws + 2*(size_t)NC;
  float* agg1h = ws + 3*(size_t)NC;
  float* agg2h = ws + 4*(size_t)NC;
  float* hr    = ws + 5*(size_t)NC;
  float* zbuf  = ws + 6*(size_t)NC;
  float* chx   = ws + 7*(size_t)NC;
  // aliases: agg buffers for hr reuse the x agg buffers (dead after GEMM1)
  float* agg1r = agg1x;
  float* agg2r = agg2x;
  float* Wbig  = ws + 8*(size_t)NC;        // 768*384
  float* Wr    = Wbig + 768*384;           // 384*128
  float* bz    = Wr + 384*128;
  float* br    = bz + 128;
  float* bht   = br + 128;
  float* dinv  = bht + 128;                // NN
  float* wv    = dinv + NN;                // EE
  int* ibase   = (int*)(wv + EE);
  int* deg     = ibase;                    // NN
  int* cnt     = deg + NN;                 // NN
  int* wo      = cnt + NN;                 // NN
  int* rowptr  = wo + NN;                  // NN+1
  int* colA    = rowptr + NN + 1;          // EE

  prep_kernel<<<NC/256, 256, 0, stream>>>(Wxz,Whz,Wxr,Whr,Wxh,Whh,
                                          bxz,bhz,bxr,bhr,bxh,bhh,
                                          Wbig,Wr,bz,br,bht,h);

  for (int t=0; t<T_STEPS; ++t){
    const int* src = edges + (size_t)t*2*EE;
    const int* dst = src + EE;
    const float* x = feat + (size_t)t*NC;

    zero_kernel<<<(2*NN+255)/256, 256, 0, stream>>>(deg, 2*NN);
    count_kernel<<<EE/256, 256, 0, stream>>>(src, dst, deg, cnt);
    dinv_kernel<<<(NN+255)/256, 256, 0, stream>>>(deg, dinv);
    scan_kernel<<<1, 1024, 0, stream>>>(cnt, rowptr, wo);
    scatter_kernel<<<EE/256, 256, 0, stream>>>(src, dst, dinv, wo, colA, wv);

    spmm_kernel<<<dim3(NN/4,2), 256, 0, stream>>>(rowptr,colA,wv, x,agg1x, h,agg1h);
    spmm_kernel<<<dim3(NN/4,2), 256, 0, stream>>>(rowptr,colA,wv, agg1x,agg2x, agg1h,agg2h);

    gemm_kernel<6,384,1><<<dim3(157,6), 256, 0, stream>>>(
        x,agg1x,agg2x,h,agg1h,agg2h, Wbig, bz,br, h, nullptr,nullptr,
        zbuf, hr, chx);

    spmm_kernel<<<dim3(NN/4,1), 256, 0, stream>>>(rowptr,colA,wv, hr,agg1r, nullptr,nullptr);
    spmm_kernel<<<dim3(NN/4,1), 256, 0, stream>>>(rowptr,colA,wv, agg1r,agg2r, nullptr,nullptr);

    gemm_kernel<3,128,2><<<dim3(157,2), 256, 0, stream>>>(
        hr,agg1r,agg2r,nullptr,nullptr,nullptr, Wr, bht,nullptr, h, chx, zbuf,
        h, nullptr, nullptr);
  }

  gemm_kernel<1,64,0><<<dim3(157,1), 256, 0, stream>>>(
      h,nullptr,nullptr,nullptr,nullptr,nullptr, Wp, bp,nullptr,
      nullptr,nullptr,nullptr, out, nullptr, nullptr);
}

// Round 3
// 1539.753 us; speedup vs baseline: 2.0593x; 2.0593x over previous
//
#include <hip/hip_runtime.h>

#define T_STEPS 10
#define NN 10000
#define EE 320000
#define CC 128
#define NC (NN*CC)

typedef unsigned short u16;
typedef unsigned int u32;
typedef __attribute__((ext_vector_type(8))) short bf16x8;
typedef __attribute__((ext_vector_type(4))) float f32x4;

__device__ __forceinline__ float sigmoidf_(float x){ return 1.f/(1.f+__expf(-x)); }
__device__ __forceinline__ float tanhf_(float x){
  x = fminf(15.f, fmaxf(-15.f, x));
  float e = __expf(2.f*x);
  return (e-1.f)/(e+1.f);
}
__device__ __forceinline__ u16 f2bf(float f){
  u32 u = __float_as_uint(f);
  u32 r = u + 0x7fffu + ((u>>16)&1u);
  return (u16)(r>>16);
}
__device__ __forceinline__ float bf2f(u16 s){
  return __uint_as_float(((u32)s)<<16);
}
__device__ __forceinline__ void gload16(const void* g, void* l){
  __builtin_amdgcn_global_load_lds(
    (const __attribute__((address_space(1))) void*)g,
    (__attribute__((address_space(3))) void*)l, 16, 0, 0);
}

// ---------------- prep: transposed bf16 effective weights + biases + h0 -----
// WbigT[384][768]: col c = gate*128+cc (z|r|h~), row k: k<384 x-side, else h-side;
//   within side blk = (k%384)>>7: 0 -> W0-W2, 1 -> W1, 2 -> 2*W2
__global__ __launch_bounds__(256) void prep_kernel(
    const float* __restrict__ Wxz, const float* __restrict__ Whz,
    const float* __restrict__ Wxr, const float* __restrict__ Whr,
    const float* __restrict__ Wxh, const float* __restrict__ Whh,
    const float* __restrict__ bxz, const float* __restrict__ bhz,
    const float* __restrict__ bxr, const float* __restrict__ bhr,
    const float* __restrict__ bxh, const float* __restrict__ bhh,
    const float* __restrict__ Wp,
    u16* __restrict__ WbigT, u16* __restrict__ WrT, u16* __restrict__ WpT,
    float* __restrict__ bz, float* __restrict__ br, float* __restrict__ bht,
    u16* __restrict__ h)
{
  int idx = blockIdx.x*256 + threadIdx.x;
  if (idx < NC) h[idx] = 0;
  if (idx < 384*768) {
    int c = idx / 768, k = idx - c*768;
    int gate = c >> 7, cc = c & 127;
    int hside = (k >= 384);
    int kk = hside ? k - 384 : k;
    int blk = kk >> 7, row = kk & 127;
    const float* W = nullptr;
    if (!hside) W = (gate==0) ? Wxz : (gate==1) ? Wxr : Wxh;
    else if (gate==0) W = Whz; else if (gate==1) W = Whr;
    float v = 0.f;
    if (W) {
      int base = row*CC + cc;
      float w0 = W[base], w1 = W[CC*CC + base], w2 = W[2*CC*CC + base];
      v = (blk==0) ? (w0 - w2) : (blk==1) ? w1 : (2.f*w2);
    }
    WbigT[idx] = f2bf(v);
  }
  if (idx < 128*384) {
    int c = idx / 384, k = idx - c*384;
    int blk = k >> 7, row = k & 127;
    int base = row*CC + c;
    float w0 = Whh[base], w1 = Whh[CC*CC+base], w2 = Whh[2*CC*CC+base];
    WrT[idx] = f2bf((blk==0) ? (w0-w2) : (blk==1) ? w1 : (2.f*w2));
  }
  if (idx < 64*128) {
    int c = idx >> 7, k = idx & 127;
    WpT[idx] = f2bf(Wp[k*64 + c]);
  }
  if (idx < CC) {
    bz[idx]  = bxz[idx] + bhz[idx];
    br[idx]  = bxr[idx] + bhr[idx];
    bht[idx] = bxh[idx] + bhh[idx];
  }
}

// fp32 -> bf16, 4 elems/thread; n4 = number of float4 chunks
__global__ __launch_bounds__(256) void xconv_kernel(const float* __restrict__ x, u16* __restrict__ xb, int n4){
  int i = blockIdx.x*256 + threadIdx.x;
  if (i >= n4) return;
  long long o = (long long)i*4;
  float4 v = *(const float4*)(x + o);
  u32 u0 = (u32)f2bf(v.x) | ((u32)f2bf(v.y)<<16);
  u32 u1 = (u32)f2bf(v.z) | ((u32)f2bf(v.w)<<16);
  uint2 r; r.x=u0; r.y=u1;
  *(uint2*)(xb + o) = r;
}

// ---------------- batched per-step graph build ----------------
__global__ __launch_bounds__(256) void zero_kernel(int* __restrict__ p, int n){
  int i = blockIdx.x*256+threadIdx.x;
  if (i<n) p[i]=0;
}

__global__ __launch_bounds__(256) void count_kernel(const int* __restrict__ edges,
                                                    int* __restrict__ deg_all, int* __restrict__ cnt_all){
  int e = blockIdx.x*256+threadIdx.x;
  int t = blockIdx.y;
  const int* src = edges + (size_t)t*2*EE;
  const int* dst = src + EE;
  int s = src[e], d = dst[e];
  if (s!=d){ atomicAdd(&deg_all[t*NN+s],1); atomicAdd(&cnt_all[t*NN+d],1); }
}

__global__ __launch_bounds__(256) void dinv_kernel(const int* __restrict__ deg_all, float* __restrict__ dinv_all){
  int i = blockIdx.x*256+threadIdx.x;
  if (i < T_STEPS*NN){ int d=deg_all[i]; dinv_all[i] = d>0 ? rsqrtf((float)d) : 0.f; }
}

// one block per timestep; shfl-based scan of cnt[NN] -> rowptr[NN+1], wo[NN]
__global__ __launch_bounds__(1024) void scan_kernel(const int* __restrict__ cnt_all,
                                                    int* __restrict__ rowptr_all, int* __restrict__ wo_all){
  int t = blockIdx.x;
  const int* cnt = cnt_all + (size_t)t*NN;
  int* rowptr = rowptr_all + (size_t)t*(NN+1);
  int* wo = wo_all + (size_t)t*NN;
  __shared__ int wsum[16];
  __shared__ int carry_s;
  int tid = threadIdx.x, lane = tid & 63, wvi = tid >> 6;
  if (tid==0) carry_s = 0;
  __syncthreads();
  for (int base=0; base<NN; base+=1024){
    int i = base+tid;
    int v = (i<NN) ? cnt[i] : 0;
    int s = v;
    #pragma unroll
    for (int off=1; off<64; off<<=1){
      int u = __shfl_up(s, off, 64);
      if (lane>=off) s += u;
    }
    if (lane==63) wsum[wvi] = s;
    __syncthreads();
    if (wvi==0 && lane<16){
      int ws = wsum[lane];
      #pragma unroll
      for (int off=1; off<16; off<<=1){
        int u = __shfl_up(ws, off, 64);
        if (lane>=off) ws += u;
      }
      wsum[lane] = ws;
    }
    __syncthreads();
    int incl = s + (wvi ? wsum[wvi-1] : 0) + carry_s;
    if (i<NN){
      rowptr[i] = incl - v;
      wo[i] = incl - v;
      if (i==NN-1) rowptr[NN] = incl;
    }
    __syncthreads();
    if (tid==1023) carry_s = incl;
    __syncthreads();
  }
}

__global__ __launch_bounds__(256) void scatter_kernel(const int* __restrict__ edges,
                                                      int* __restrict__ wo_all,
                                                      int* __restrict__ colA_all){
  int e = blockIdx.x*256+threadIdx.x;
  int t = blockIdx.y;
  const int* src = edges + (size_t)t*2*EE;
  const int* dst = src + EE;
  int s = src[e], d = dst[e];
  if (s!=d){
    int pos = atomicAdd(&wo_all[t*NN+d],1);
    colA_all[(size_t)t*EE+pos] = s;
  }
}

// ---------------- CSR SpMM bf16: out[d,:] = sum -dinv[d]dinv[s] in[s,:] ----
__global__ __launch_bounds__(256) void spmm_kernel(const int* __restrict__ rowptr, const int* __restrict__ colA,
                                                   const float* __restrict__ dinv,
                                                   const u16* __restrict__ in0, u16* __restrict__ out0,
                                                   const u16* __restrict__ in1, u16* __restrict__ out1){
  int wave = threadIdx.x >> 6, lane = threadIdx.x & 63;
  int row = blockIdx.x*4 + wave;
  const u16* __restrict__ in = blockIdx.y ? in1 : in0;
  u16* __restrict__ out = blockIdx.y ? out1 : out0;
  if (row >= NN) return;
  int k0 = rowptr[row], k1 = rowptr[row+1];
  float wrow = -dinv[row];
  float ax=0.f, ay=0.f;
  #pragma unroll 4
  for (int k=k0;k<k1;k++){
    int s = colA[k];
    float w = wrow * dinv[s];
    u32 u = *(const u32*)(in + (size_t)s*CC + lane*2);
    ax = fmaf(w, __uint_as_float(u<<16), ax);
    ay = fmaf(w, __uint_as_float(u & 0xffff0000u), ay);
  }
  u32 res = (u32)f2bf(ax) | ((u32)f2bf(ay)<<16);
  *(u32*)(out + (size_t)row*CC + lane*2) = res;
}

// ---------------- bf16 MFMA GEMM: C[m, n] over segmented K -----------------
// BM=BN=64, BK=64, 256 thr = 4 waves, each wave a 32x32 quadrant (2x2 frags).
// A segs: row-major [NN][128] bf16.  Bt: [NCOLS][KDIM] bf16 (pre-transposed).
// LDS tiles [64 rows][8 x 16B chunks], XOR swizzle chunk^=(row&7), staged by
// global_load_lds with pre-swizzled SOURCE (both-sides rule #21).
// EPI 0: out_f[r*64+c] = acc + bias0[c]
// EPI 1: gate=col>>7: 0 z=sigmoid(+bz)->zbuf(f32); 1 hr=sigmoid(+br)*h (bf16); 2 chx=acc(f32)
// EPI 2: h = z*h + (1-z)*tanh(acc + chx + bht)   (bf16, in-place)
template<int NSEG, int KDIM, int EPI>
__global__ __launch_bounds__(256) void mgemm_kernel(
    const u16* __restrict__ A0, const u16* __restrict__ A1, const u16* __restrict__ A2,
    const u16* __restrict__ A3, const u16* __restrict__ A4, const u16* __restrict__ A5,
    const u16* __restrict__ Bt,
    const float* __restrict__ bias0, const float* __restrict__ bias1,
    const u16* __restrict__ hbuf,
    float* __restrict__ zbuf, float* __restrict__ chx,
    u16* __restrict__ hr_out, u16* __restrict__ h_out,
    float* __restrict__ out_f)
{
  __shared__ __align__(16) u16 As[64*64];
  __shared__ __align__(16) u16 Bs[64*64];
  const u16* segs[6] = {A0,A1,A2,A3,A4,A5};
  int tid = threadIdx.x, lane = tid & 63, wvi = tid >> 6;
  int m0 = blockIdx.x*64, n0 = blockIdx.y*64;
  int wr = wvi >> 1, wc = wvi & 1;

  f32x4 acc[2][2] = {};

  // staging: 512 16B chunks/tile; chunk id c0 = wvi*64+lane -> LDS linear.
  // tile row r0 = c0>>3 (first half; +32 second), slot cc0 = c0&7.
  // source chunk scw = cc0 ^ (r0&7)  (inverse-swizzled source, linear dest)
  int c0 = wvi*64 + lane;
  int r0 = c0 >> 3, cc0 = c0 & 7;
  int scw = cc0 ^ (r0 & 7);
  int grow0 = m0 + r0;      if (grow0 > NN-1) grow0 = NN-1;
  int grow1 = m0 + r0 + 32; if (grow1 > NN-1) grow1 = NN-1;
  int nrow0 = n0 + r0, nrow1 = nrow0 + 32;
  u16* ldsA0 = (u16*)As + (size_t)wvi*64*8;   // wave-uniform base + lane*16B
  u16* ldsA1 = ldsA0 + 256*8;
  u16* ldsB0 = (u16*)Bs + (size_t)wvi*64*8;
  u16* ldsB1 = ldsB0 + 256*8;

  // fragment read offsets (bytes); same XOR on the 16B-chunk index
  int rl = lane & 15, rg = lane >> 4, sw = rl & 7;
  int rowa0 = wr*32 + rl, rowb0 = wc*32 + rl;
  int offA[2][2], offB[2][2];
  #pragma unroll
  for (int mf=0; mf<2; ++mf)
    #pragma unroll
    for (int ks=0; ks<2; ++ks){
      offA[mf][ks] = (rowa0 + mf*16)*128 + ((((ks<<2)+rg) ^ sw)<<4);
      offB[mf][ks] = (rowb0 + mf*16)*128 + ((((ks<<2)+rg) ^ sw)<<4);
    }

  for (int kt=0; kt<NSEG*2; ++kt){
    const u16* __restrict__ Aseg = segs[kt>>1];
    int ko = (kt&1)*64;
    __syncthreads();  // previous iteration's LDS reads done before overwrite
    gload16(Aseg + (size_t)grow0*CC + ko + scw*8, ldsA0);
    gload16(Aseg + (size_t)grow1*CC + ko + scw*8, ldsA1);
    gload16(Bt + (size_t)nrow0*KDIM + kt*64 + scw*8, ldsB0);
    gload16(Bt + (size_t)nrow1*KDIM + kt*64 + scw*8, ldsB1);
    __syncthreads();  // compiler drains vmcnt before s_barrier -> data ready
    #pragma unroll
    for (int ks=0; ks<2; ++ks){
      bf16x8 a0 = *(const bf16x8*)((const char*)As + offA[0][ks]);
      bf16x8 a1 = *(const bf16x8*)((const char*)As + offA[1][ks]);
      bf16x8 b0 = *(const bf16x8*)((const char*)Bs + offB[0][ks]);
      bf16x8 b1 = *(const bf16x8*)((const char*)Bs + offB[1][ks]);
      acc[0][0] = __builtin_amdgcn_mfma_f32_16x16x32_bf16(a0, b0, acc[0][0], 0,0,0);
      acc[0][1] = __builtin_amdgcn_mfma_f32_16x16x32_bf16(a0, b1, acc[0][1], 0,0,0);
      acc[1][0] = __builtin_amdgcn_mfma_f32_16x16x32_bf16(a1, b0, acc[1][0], 0,0,0);
      acc[1][1] = __builtin_amdgcn_mfma_f32_16x16x32_bf16(a1, b1, acc[1][1], 0,0,0);
    }
  }

  // epilogue: C/D layout col=lane&15, row=(lane>>4)*4+reg  [guide m89]
  #pragma unroll
  for (int mf=0; mf<2; ++mf){
    #pragma unroll
    for (int nf=0; nf<2; ++nf){
      #pragma unroll
      for (int r=0; r<4; ++r){
        int grow = m0 + wr*32 + mf*16 + rg*4 + r;
        if (grow >= NN) continue;
        int gcol = n0 + wc*32 + nf*16 + rl;
        float v = acc[mf][nf][r];
        if (EPI==0){
          out_f[(size_t)grow*64 + gcol] = v + bias0[gcol];
        } else if (EPI==1){
          int gate = gcol >> 7, c = gcol & 127;
          size_t idx = (size_t)grow*CC + c;
          if (gate==0)      zbuf[idx] = sigmoidf_(v + bias0[c]);
          else if (gate==1){
            float rr = sigmoidf_(v + bias1[c]);
            hr_out[idx] = f2bf(rr * bf2f(hbuf[idx]));
          } else            chx[idx] = v;
        } else {
          size_t idx = (size_t)grow*CC + gcol;
          float pre = v + chx[idx] + bias0[gcol];
          float ht = tanhf_(pre);
          float zz = zbuf[idx];
          float hv = bf2f(hbuf[idx]);
          h_out[idx] = f2bf(fmaf(zz, hv - ht, ht));
        }
      }
    }
  }
}

extern "C" void kernel_launch(void* const* d_in, const int* in_sizes, int n_in,
                              void* d_out, int out_size, void* d_ws, size_t ws_size,
                              hipStream_t stream)
{
  (void)in_sizes; (void)n_in; (void)out_size;
  const float* feat = (const float*)d_in[0];
  const int*   edges = (const int*)d_in[1];
  const float* Wxz=(const float*)d_in[2];  const float* bxz=(const float*)d_in[3];
  const float* Whz=(const float*)d_in[4];  const float* bhz=(const float*)d_in[5];
  const float* Wxr=(const float*)d_in[6];  const float* bxr=(const float*)d_in[7];
  const float* Whr=(const float*)d_in[8];  const float* bhr=(const float*)d_in[9];
  const float* Wxh=(const float*)d_in[10]; const float* bxh=(const float*)d_in[11];
  const float* Whh=(const float*)d_in[12]; const float* bhh=(const float*)d_in[13];
  const float* Wp =(const float*)d_in[14]; const float* bp =(const float*)d_in[15];
  float* out = (float*)d_out;

  // footprint: full-T bf16 feature buffer only if workspace is roomy;
  // fallback path stays within the round-1-proven ~44MB envelope.
  const bool full_xb = ws_size >= (size_t)100*1024*1024;

  char* p = (char*)d_ws;
  auto alloc = [&](size_t bytes)->char* {
    char* r = p; p += (bytes + 255) & ~(size_t)255; return r;
  };
  u16* xb   = (u16*)alloc((full_xb ? (size_t)T_STEPS : 1)*(size_t)NC*2);
  u16* h    = (u16*)alloc((size_t)NC*2);
  u16* a1x  = (u16*)alloc((size_t)NC*2);
  u16* a2x  = (u16*)alloc((size_t)NC*2);
  u16* a1h  = (u16*)alloc((size_t)NC*2);
  u16* a2h  = (u16*)alloc((size_t)NC*2);
  u16* hr   = (u16*)alloc((size_t)NC*2);
  float* zbuf = (float*)alloc((size_t)NC*4);
  float* chx  = (float*)alloc((size_t)NC*4);
  u16* WbigT = (u16*)alloc(384*768*2);
  u16* WrT   = (u16*)alloc(128*384*2);
  u16* WpT   = (u16*)alloc(64*128*2);
  float* bz  = (float*)alloc(CC*4);
  float* br  = (float*)alloc(CC*4);
  float* bht = (float*)alloc(CC*4);
  float* dinv_all = (float*)alloc((size_t)T_STEPS*NN*4);
  int* degcnt     = (int*)alloc((size_t)2*T_STEPS*NN*4);  // deg | cnt contiguous
  int* deg_all    = degcnt;
  int* cnt_all    = degcnt + (size_t)T_STEPS*NN;
  int* wo_all     = (int*)alloc((size_t)T_STEPS*NN*4);
  int* rowptr_all = (int*)alloc((size_t)T_STEPS*(NN+1)*4);
  int* colA_all   = (int*)alloc((size_t)T_STEPS*EE*4);
  // hr-path agg buffers alias the x-path ones (dead after GEMM1)
  u16* a1r = a1x;
  u16* a2r = a2x;

  prep_kernel<<<NC/256, 256, 0, stream>>>(Wxz,Whz,Wxr,Whr,Wxh,Whh,
                                          bxz,bhz,bxr,bhr,bxh,bhh, Wp,
                                          WbigT, WrT, WpT, bz, br, bht, h);
  if (full_xb)
    xconv_kernel<<<(T_STEPS*NC/4 + 255)/256, 256, 0, stream>>>(feat, xb, T_STEPS*NC/4);

  zero_kernel<<<(2*T_STEPS*NN+255)/256, 256, 0, stream>>>(degcnt, 2*T_STEPS*NN);
  count_kernel<<<dim3(EE/256, T_STEPS), 256, 0, stream>>>(edges, deg_all, cnt_all);
  dinv_kernel<<<(T_STEPS*NN+255)/256, 256, 0, stream>>>(deg_all, dinv_all);
  scan_kernel<<<T_STEPS, 1024, 0, stream>>>(cnt_all, rowptr_all, wo_all);
  scatter_kernel<<<dim3(EE/256, T_STEPS), 256, 0, stream>>>(edges, wo_all, colA_all);

  for (int t=0; t<T_STEPS; ++t){
    const int*   rowptr = rowptr_all + (size_t)t*(NN+1);
    const int*   colA   = colA_all + (size_t)t*EE;
    const float* dinv   = dinv_all + (size_t)t*NN;
    const u16*   x;
    if (full_xb){
      x = xb + (size_t)t*NC;
    } else {
      xconv_kernel<<<(NC/4 + 255)/256, 256, 0, stream>>>(feat + (size_t)t*NC, xb, NC/4);
      x = xb;
    }

    spmm_kernel<<<dim3(NN/4,2), 256, 0, stream>>>(rowptr,colA,dinv, x,a1x, h,a1h);
    spmm_kernel<<<dim3(NN/4,2), 256, 0, stream>>>(rowptr,colA,dinv, a1x,a2x, a1h,a2h);

    mgemm_kernel<6,768,1><<<dim3(157,6), 256, 0, stream>>>(
        x,a1x,a2x,h,a1h,a2h, WbigT, bz, br, h, zbuf, chx, hr, nullptr, nullptr);

    spmm_kernel<<<dim3(NN/4,1), 256, 0, stream>>>(rowptr,colA,dinv, hr,a1r, nullptr,nullptr);
    spmm_kernel<<<dim3(NN/4,1), 256, 0, stream>>>(rowptr,colA,dinv, a1r,a2r, nullptr,nullptr);

    mgemm_kernel<3,384,2><<<dim3(157,2), 256, 0, stream>>>(
        hr,a1r,a2r,nullptr,nullptr,nullptr, WrT, bht, nullptr, h, zbuf, chx,
        nullptr, h, nullptr);
  }

  mgemm_kernel<1,128,0><<<dim3(157,1), 256, 0, stream>>>(
      h,nullptr,nullptr,nullptr,nullptr,nullptr, WpT, bp, nullptr,
      nullptr, nullptr, nullptr, nullptr, nullptr, out);
}

// Round 4
// 1214.781 us; speedup vs baseline: 2.6102x; 1.2675x over previous
//
#include <hip/hip_runtime.h>

#define T_STEPS 10
#define NN 10000
#define EE 320000
#define CC 128
#define NC (NN*CC)
#define BHIST 8
#define EPB (EE/BHIST)   // 40000 edges per hist/place block

typedef unsigned short u16;
typedef unsigned int u32;
typedef __attribute__((ext_vector_type(8))) short bf16x8;
typedef __attribute__((ext_vector_type(4))) float f32x4;

__device__ __forceinline__ float sigmoidf_(float x){ return 1.f/(1.f+__expf(-x)); }
__device__ __forceinline__ float tanhf_(float x){
  x = fminf(15.f, fmaxf(-15.f, x));
  float e = __expf(2.f*x);
  return (e-1.f)/(e+1.f);
}
__device__ __forceinline__ u16 f2bf(float f){
  u32 u = __float_as_uint(f);
  u32 r = u + 0x7fffu + ((u>>16)&1u);
  return (u16)(r>>16);
}
__device__ __forceinline__ float bf2f(u16 s){
  return __uint_as_float(((u32)s)<<16);
}
__device__ __forceinline__ void gload16(const void* g, void* l){
  __builtin_amdgcn_global_load_lds(
    (const __attribute__((address_space(1))) void*)g,
    (__attribute__((address_space(3))) void*)l, 16, 0, 0);
}

// ---------------- prep: transposed bf16 effective weights + biases + h0 -----
__global__ __launch_bounds__(256) void prep_kernel(
    const float* __restrict__ Wxz, const float* __restrict__ Whz,
    const float* __restrict__ Wxr, const float* __restrict__ Whr,
    const float* __restrict__ Wxh, const float* __restrict__ Whh,
    const float* __restrict__ bxz, const float* __restrict__ bhz,
    const float* __restrict__ bxr, const float* __restrict__ bhr,
    const float* __restrict__ bxh, const float* __restrict__ bhh,
    const float* __restrict__ Wp,
    u16* __restrict__ WbigT, u16* __restrict__ WrT, u16* __restrict__ WpT,
    float* __restrict__ bz, float* __restrict__ br, float* __restrict__ bht,
    u16* __restrict__ h)
{
  int idx = blockIdx.x*256 + threadIdx.x;
  if (idx < NC) h[idx] = 0;
  if (idx < 384*768) {
    int c = idx / 768, k = idx - c*768;
    int gate = c >> 7, cc = c & 127;
    int hside = (k >= 384);
    int kk = hside ? k - 384 : k;
    int blk = kk >> 7, row = kk & 127;
    const float* W = nullptr;
    if (!hside) W = (gate==0) ? Wxz : (gate==1) ? Wxr : Wxh;
    else if (gate==0) W = Whz; else if (gate==1) W = Whr;
    float v = 0.f;
    if (W) {
      int base = row*CC + cc;
      float w0 = W[base], w1 = W[CC*CC + base], w2 = W[2*CC*CC + base];
      v = (blk==0) ? (w0 - w2) : (blk==1) ? w1 : (2.f*w2);
    }
    WbigT[idx] = f2bf(v);
  }
  if (idx < 128*384) {
    int c = idx / 384, k = idx - c*384;
    int blk = k >> 7, row = k & 127;
    int base = row*CC + c;
    float w0 = Whh[base], w1 = Whh[CC*CC+base], w2 = Whh[2*CC*CC+base];
    WrT[idx] = f2bf((blk==0) ? (w0-w2) : (blk==1) ? w1 : (2.f*w2));
  }
  if (idx < 64*128) {
    int c = idx >> 7, k = idx & 127;
    WpT[idx] = f2bf(Wp[k*64 + c]);
  }
  if (idx < CC) {
    bz[idx]  = bxz[idx] + bhz[idx];
    br[idx]  = bxr[idx] + bhr[idx];
    bht[idx] = bxh[idx] + bhh[idx];
  }
}

// fp32 -> bf16, 4 elems/thread; n4 = number of float4 chunks
__global__ __launch_bounds__(256) void xconv_kernel(const float* __restrict__ x, u16* __restrict__ xb, int n4){
  int i = blockIdx.x*256 + threadIdx.x;
  if (i >= n4) return;
  long long o = (long long)i*4;
  float4 v = *(const float4*)(x + o);
  u32 u0 = (u32)f2bf(v.x) | ((u32)f2bf(v.y)<<16);
  u32 u1 = (u32)f2bf(v.z) | ((u32)f2bf(v.w)<<16);
  uint2 r; r.x=u0; r.y=u1;
  *(uint2*)(xb + o) = r;
}

// ---------------- graph build: LDS histograms, zero global atomics ---------
// hist_kernel: block (b,t) histograms its EPB edges in LDS (deg over src,
// cnt over dst, self-loops excluded), writes per-block partials.
__global__ __launch_bounds__(256) void hist_kernel(const int* __restrict__ edges,
                                                   int* __restrict__ histD, int* __restrict__ histC){
  __shared__ int hist[2*NN];   // 80 KB: [0,NN)=deg(src), [NN,2NN)=cnt(dst)
  int t = blockIdx.y, b = blockIdx.x, tid = threadIdx.x;
  for (int i = tid; i < 2*NN; i += 256) hist[i] = 0;
  __syncthreads();
  const int* src = edges + (size_t)t*2*EE;
  const int* dst = src + EE;
  int e1 = b*EPB + EPB;
  for (int e = b*EPB + tid; e < e1; e += 256){
    int s = src[e], d = dst[e];
    if (s != d){
      atomicAdd(&hist[s], 1);        // ds_add, LDS-local
      atomicAdd(&hist[NN + d], 1);
    }
  }
  __syncthreads();
  int* hd = histD + ((size_t)t*BHIST + b)*NN;
  int* hc = histC + ((size_t)t*BHIST + b)*NN;
  for (int i = tid; i < NN; i += 256){ hd[i] = hist[i]; hc[i] = hist[NN+i]; }
}

// reduce_kernel: per (t,d): deg total -> dinv; exclusive prefix over the
// BHIST cnt partials (in place -> per-block base), total -> cnt_all.
__global__ __launch_bounds__(256) void reduce_kernel(const int* __restrict__ histD, int* __restrict__ histC,
                                                     int* __restrict__ cnt_all, float* __restrict__ dinv_all){
  int t = blockIdx.y;
  int d = blockIdx.x*256 + threadIdx.x;
  if (d >= NN) return;
  size_t base = (size_t)t*BHIST*NN + d;
  int run = 0, degs = 0;
  #pragma unroll
  for (int b = 0; b < BHIST; ++b){
    size_t ix = base + (size_t)b*NN;
    int v = histC[ix];
    histC[ix] = run;
    run += v;
    degs += histD[ix];
  }
  cnt_all[t*NN + d] = run;
  dinv_all[t*NN + d] = degs > 0 ? rsqrtf((float)degs) : 0.f;
}

// one block per timestep; shfl-based scan of cnt[NN] -> rowptr[NN+1]
__global__ __launch_bounds__(1024) void scan_kernel(const int* __restrict__ cnt_all,
                                                    int* __restrict__ rowptr_all){
  int t = blockIdx.x;
  const int* cnt = cnt_all + (size_t)t*NN;
  int* rowptr = rowptr_all + (size_t)t*(NN+1);
  __shared__ int wsum[16];
  __shared__ int carry_s;
  int tid = threadIdx.x, lane = tid & 63, wvi = tid >> 6;
  if (tid==0) carry_s = 0;
  __syncthreads();
  for (int base=0; base<NN; base+=1024){
    int i = base+tid;
    int v = (i<NN) ? cnt[i] : 0;
    int s = v;
    #pragma unroll
    for (int off=1; off<64; off<<=1){
      int u = __shfl_up(s, off, 64);
      if (lane>=off) s += u;
    }
    if (lane==63) wsum[wvi] = s;
    __syncthreads();
    if (wvi==0 && lane<16){
      int ws = wsum[lane];
      #pragma unroll
      for (int off=1; off<16; off<<=1){
        int u = __shfl_up(ws, off, 64);
        if (lane>=off) ws += u;
      }
      wsum[lane] = ws;
    }
    __syncthreads();
    int incl = s + (wvi ? wsum[wvi-1] : 0) + carry_s;
    if (i<NN){
      rowptr[i] = incl - v;
      if (i==NN-1) rowptr[NN] = incl;
    }
    __syncthreads();
    if (tid==1023) carry_s = incl;
    __syncthreads();
  }
}

// place_kernel: counting-sort scatter. Block (b,t) seeds LDS counters with
// rowptr[d] + its exclusive base, ranks its edges via LDS atomics, writes colA.
__global__ __launch_bounds__(256) void place_kernel(const int* __restrict__ edges,
                                                    const int* __restrict__ rowptr_all,
                                                    const int* __restrict__ histC,
                                                    int* __restrict__ colA_all){
  __shared__ int slot[NN];     // 40 KB
  int t = blockIdx.y, b = blockIdx.x, tid = threadIdx.x;
  const int* rowptr = rowptr_all + (size_t)t*(NN+1);
  const int* hc = histC + ((size_t)t*BHIST + b)*NN;
  for (int i = tid; i < NN; i += 256) slot[i] = rowptr[i] + hc[i];
  __syncthreads();
  const int* src = edges + (size_t)t*2*EE;
  const int* dst = src + EE;
  int* colA = colA_all + (size_t)t*EE;
  int e1 = b*EPB + EPB;
  for (int e = b*EPB + tid; e < e1; e += 256){
    int s = src[e], d = dst[e];
    if (s != d){
      int pos = atomicAdd(&slot[d], 1);   // LDS atomic, returns rank
      colA[pos] = s;
    }
  }
}

// ---------------- CSR SpMM bf16: out[d,:] = sum -dinv[d]dinv[s] in[s,:] ----
// single-input variant (hr path)
__global__ __launch_bounds__(256) void spmm_kernel(const int* __restrict__ rowptr, const int* __restrict__ colA,
                                                   const float* __restrict__ dinv,
                                                   const u16* __restrict__ in, u16* __restrict__ out){
  int wave = threadIdx.x >> 6, lane = threadIdx.x & 63;
  int row = blockIdx.x*4 + wave;
  if (row >= NN) return;
  int k0 = rowptr[row], k1 = rowptr[row+1];
  float wrow = -dinv[row];
  float ax=0.f, ay=0.f;
  #pragma unroll 4
  for (int k=k0;k<k1;k++){
    int s = colA[k];
    float w = wrow * dinv[s];
    u32 u = *(const u32*)(in + (size_t)s*CC + lane*2);
    ax = fmaf(w, __uint_as_float(u<<16), ax);
    ay = fmaf(w, __uint_as_float(u & 0xffff0000u), ay);
  }
  u32 res = (u32)f2bf(ax) | ((u32)f2bf(ay)<<16);
  *(u32*)(out + (size_t)row*CC + lane*2) = res;
}

// dual-input variant, XCD-pinned: blocks with (bid&7)<4 process input0 on
// XCDs 0-3, others input1 on XCDs 4-7 -> each XCD's L2 holds one 2.5MB matrix.
__global__ __launch_bounds__(256) void spmm2_kernel(const int* __restrict__ rowptr, const int* __restrict__ colA,
                                                    const float* __restrict__ dinv,
                                                    const u16* __restrict__ in0, u16* __restrict__ out0,
                                                    const u16* __restrict__ in1, u16* __restrict__ out1){
  int wave = threadIdx.x >> 6, lane = threadIdx.x & 63;
  int bid = blockIdx.x;
  int xcd = bid & 7;
  int inp = xcd >> 2;
  int wb  = (bid >> 3)*4 + (xcd & 3);   // [0, NN/4)
  int row = wb*4 + wave;
  const u16* __restrict__ in = inp ? in1 : in0;
  u16* __restrict__ out = inp ? out1 : out0;
  if (row >= NN) return;
  int k0 = rowptr[row], k1 = rowptr[row+1];
  float wrow = -dinv[row];
  float ax=0.f, ay=0.f;
  #pragma unroll 4
  for (int k=k0;k<k1;k++){
    int s = colA[k];
    float w = wrow * dinv[s];
    u32 u = *(const u32*)(in + (size_t)s*CC + lane*2);
    ax = fmaf(w, __uint_as_float(u<<16), ax);
    ay = fmaf(w, __uint_as_float(u & 0xffff0000u), ay);
  }
  u32 res = (u32)f2bf(ax) | ((u32)f2bf(ay)<<16);
  *(u32*)(out + (size_t)row*CC + lane*2) = res;
}

// ---------------- bf16 MFMA GEMM: C[m, n] over segmented K -----------------
// BM=BN=64, BK=64, 4 waves, each wave a 32x32 quadrant (2x2 frags).
// LDS tiles [64 rows][8 x 16B chunks], XOR swizzle chunk^=(row&7), staged by
// global_load_lds with pre-swizzled SOURCE (both-sides rule #21).
template<int NSEG, int KDIM, int EPI>
__global__ __launch_bounds__(256) void mgemm_kernel(
    const u16* __restrict__ A0, const u16* __restrict__ A1, const u16* __restrict__ A2,
    const u16* __restrict__ A3, const u16* __restrict__ A4, const u16* __restrict__ A5,
    const u16* __restrict__ Bt,
    const float* __restrict__ bias0, const float* __restrict__ bias1,
    const u16* __restrict__ hbuf,
    float* __restrict__ zbuf, float* __restrict__ chx,
    u16* __restrict__ hr_out, u16* __restrict__ h_out,
    float* __restrict__ out_f)
{
  __shared__ __align__(16) u16 As[64*64];
  __shared__ __align__(16) u16 Bs[64*64];
  const u16* segs[6] = {A0,A1,A2,A3,A4,A5};
  int tid = threadIdx.x, lane = tid & 63, wvi = tid >> 6;
  int m0 = blockIdx.x*64, n0 = blockIdx.y*64;
  int wr = wvi >> 1, wc = wvi & 1;

  f32x4 acc[2][2] = {};

  int c0 = wvi*64 + lane;
  int r0 = c0 >> 3, cc0 = c0 & 7;
  int scw = cc0 ^ (r0 & 7);
  int grow0 = m0 + r0;      if (grow0 > NN-1) grow0 = NN-1;
  int grow1 = m0 + r0 + 32; if (grow1 > NN-1) grow1 = NN-1;
  int nrow0 = n0 + r0, nrow1 = nrow0 + 32;
  u16* ldsA0 = (u16*)As + (size_t)wvi*64*8;
  u16* ldsA1 = ldsA0 + 256*8;
  u16* ldsB0 = (u16*)Bs + (size_t)wvi*64*8;
  u16* ldsB1 = ldsB0 + 256*8;

  int rl = lane & 15, rg = lane >> 4, sw = rl & 7;
  int rowa0 = wr*32 + rl, rowb0 = wc*32 + rl;
  int offA[2][2], offB[2][2];
  #pragma unroll
  for (int mf=0; mf<2; ++mf)
    #pragma unroll
    for (int ks=0; ks<2; ++ks){
      offA[mf][ks] = (rowa0 + mf*16)*128 + ((((ks<<2)+rg) ^ sw)<<4);
      offB[mf][ks] = (rowb0 + mf*16)*128 + ((((ks<<2)+rg) ^ sw)<<4);
    }

  for (int kt=0; kt<NSEG*2; ++kt){
    const u16* __restrict__ Aseg = segs[kt>>1];
    int ko = (kt&1)*64;
    __syncthreads();
    gload16(Aseg + (size_t)grow0*CC + ko + scw*8, ldsA0);
    gload16(Aseg + (size_t)grow1*CC + ko + scw*8, ldsA1);
    gload16(Bt + (size_t)nrow0*KDIM + kt*64 + scw*8, ldsB0);
    gload16(Bt + (size_t)nrow1*KDIM + kt*64 + scw*8, ldsB1);
    __syncthreads();
    #pragma unroll
    for (int ks=0; ks<2; ++ks){
      bf16x8 a0 = *(const bf16x8*)((const char*)As + offA[0][ks]);
      bf16x8 a1 = *(const bf16x8*)((const char*)As + offA[1][ks]);
      bf16x8 b0 = *(const bf16x8*)((const char*)Bs + offB[0][ks]);
      bf16x8 b1 = *(const bf16x8*)((const char*)Bs + offB[1][ks]);
      acc[0][0] = __builtin_amdgcn_mfma_f32_16x16x32_bf16(a0, b0, acc[0][0], 0,0,0);
      acc[0][1] = __builtin_amdgcn_mfma_f32_16x16x32_bf16(a0, b1, acc[0][1], 0,0,0);
      acc[1][0] = __builtin_amdgcn_mfma_f32_16x16x32_bf16(a1, b0, acc[1][0], 0,0,0);
      acc[1][1] = __builtin_amdgcn_mfma_f32_16x16x32_bf16(a1, b1, acc[1][1], 0,0,0);
    }
  }

  // epilogue: C/D layout col=lane&15, row=(lane>>4)*4+reg  [guide m89]
  #pragma unroll
  for (int mf=0; mf<2; ++mf){
    #pragma unroll
    for (int nf=0; nf<2; ++nf){
      #pragma unroll
      for (int r=0; r<4; ++r){
        int grow = m0 + wr*32 + mf*16 + rg*4 + r;
        if (grow >= NN) continue;
        int gcol = n0 + wc*32 + nf*16 + rl;
        float v = acc[mf][nf][r];
        if (EPI==0){
          out_f[(size_t)grow*64 + gcol] = v + bias0[gcol];
        } else if (EPI==1){
          int gate = gcol >> 7, c = gcol & 127;
          size_t idx = (size_t)grow*CC + c;
          if (gate==0)      zbuf[idx] = sigmoidf_(v + bias0[c]);
          else if (gate==1){
            float rr = sigmoidf_(v + bias1[c]);
            hr_out[idx] = f2bf(rr * bf2f(hbuf[idx]));
          } else            chx[idx] = v;
        } else {
          size_t idx = (size_t)grow*CC + gcol;
          float pre = v + chx[idx] + bias0[gcol];
          float ht = tanhf_(pre);
          float zz = zbuf[idx];
          float hv = bf2f(hbuf[idx]);
          h_out[idx] = f2bf(fmaf(zz, hv - ht, ht));
        }
      }
    }
  }
}

extern "C" void kernel_launch(void* const* d_in, const int* in_sizes, int n_in,
                              void* d_out, int out_size, void* d_ws, size_t ws_size,
                              hipStream_t stream)
{
  (void)in_sizes; (void)n_in; (void)out_size;
  const float* feat = (const float*)d_in[0];
  const int*   edges = (const int*)d_in[1];
  const float* Wxz=(const float*)d_in[2];  const float* bxz=(const float*)d_in[3];
  const float* Whz=(const float*)d_in[4];  const float* bhz=(const float*)d_in[5];
  const float* Wxr=(const float*)d_in[6];  const float* bxr=(const float*)d_in[7];
  const float* Whr=(const float*)d_in[8];  const float* bhr=(const float*)d_in[9];
  const float* Wxh=(const float*)d_in[10]; const float* bxh=(const float*)d_in[11];
  const float* Whh=(const float*)d_in[12]; const float* bhh=(const float*)d_in[13];
  const float* Wp =(const float*)d_in[14]; const float* bp =(const float*)d_in[15];
  float* out = (float*)d_out;

  const bool full_xb = ws_size >= (size_t)100*1024*1024;

  char* p = (char*)d_ws;
  auto alloc = [&](size_t bytes)->char* {
    char* r = p; p += (bytes + 255) & ~(size_t)255; return r;
  };
  u16* xb   = (u16*)alloc((full_xb ? (size_t)T_STEPS : 1)*(size_t)NC*2);
  u16* h    = (u16*)alloc((size_t)NC*2);
  u16* a1x  = (u16*)alloc((size_t)NC*2);
  u16* a2x  = (u16*)alloc((size_t)NC*2);
  u16* a1h  = (u16*)alloc((size_t)NC*2);
  u16* a2h  = (u16*)alloc((size_t)NC*2);
  u16* hr   = (u16*)alloc((size_t)NC*2);
  float* zbuf = (float*)alloc((size_t)NC*4);
  float* chx  = (float*)alloc((size_t)NC*4);
  u16* WbigT = (u16*)alloc(384*768*2);
  u16* WrT   = (u16*)alloc(128*384*2);
  u16* WpT   = (u16*)alloc(64*128*2);
  float* bz  = (float*)alloc(CC*4);
  float* br  = (float*)alloc(CC*4);
  float* bht = (float*)alloc(CC*4);
  float* dinv_all = (float*)alloc((size_t)T_STEPS*NN*4);
  int* cnt_all    = (int*)alloc((size_t)T_STEPS*NN*4);
  int* rowptr_all = (int*)alloc((size_t)T_STEPS*(NN+1)*4);
  int* colA_all   = (int*)alloc((size_t)T_STEPS*EE*4);
  // hist partials alias zbuf+chx (contiguous 10.24MB >= 6.4MB; hists are dead
  // before the recurrence loop first writes zbuf/chx)
  int* histD = (int*)zbuf;
  int* histC = histD + (size_t)T_STEPS*BHIST*NN;
  // hr-path agg buffers alias the x-path ones (dead after GEMM1)
  u16* a1r = a1x;
  u16* a2r = a2x;

  prep_kernel<<<NC/256, 256, 0, stream>>>(Wxz,Whz,Wxr,Whr,Wxh,Whh,
                                          bxz,bhz,bxr,bhr,bxh,bhh, Wp,
                                          WbigT, WrT, WpT, bz, br, bht, h);
  if (full_xb)
    xconv_kernel<<<(T_STEPS*NC/4 + 255)/256, 256, 0, stream>>>(feat, xb, T_STEPS*NC/4);

  hist_kernel<<<dim3(BHIST, T_STEPS), 256, 0, stream>>>(edges, histD, histC);
  reduce_kernel<<<dim3((NN+255)/256, T_STEPS), 256, 0, stream>>>(histD, histC, cnt_all, dinv_all);
  scan_kernel<<<T_STEPS, 1024, 0, stream>>>(cnt_all, rowptr_all);
  place_kernel<<<dim3(BHIST, T_STEPS), 256, 0, stream>>>(edges, rowptr_all, histC, colA_all);

  for (int t=0; t<T_STEPS; ++t){
    const int*   rowptr = rowptr_all + (size_t)t*(NN+1);
    const int*   colA   = colA_all + (size_t)t*EE;
    const float* dinv   = dinv_all + (size_t)t*NN;
    const u16*   x;
    if (full_xb){
      x = xb + (size_t)t*NC;
    } else {
      xconv_kernel<<<(NC/4 + 255)/256, 256, 0, stream>>>(feat + (size_t)t*NC, xb, NC/4);
      x = xb;
    }

    spmm2_kernel<<<dim3(2*(NN/4)), 256, 0, stream>>>(rowptr,colA,dinv, x,a1x, h,a1h);
    spmm2_kernel<<<dim3(2*(NN/4)), 256, 0, stream>>>(rowptr,colA,dinv, a1x,a2x, a1h,a2h);

    mgemm_kernel<6,768,1><<<dim3(157,6), 256, 0, stream>>>(
        x,a1x,a2x,h,a1h,a2h, WbigT, bz, br, h, zbuf, chx, hr, nullptr, nullptr);

    spmm_kernel<<<dim3(NN/4), 256, 0, stream>>>(rowptr,colA,dinv, hr,a1r);
    spmm_kernel<<<dim3(NN/4), 256, 0, stream>>>(rowptr,colA,dinv, a1r,a2r);

    mgemm_kernel<3,384,2><<<dim3(157,2), 256, 0, stream>>>(
        hr,a1r,a2r,nullptr,nullptr,nullptr, WrT, bht, nullptr, h, zbuf, chx,
        nullptr, h, nullptr);
  }

  mgemm_kernel<1,128,0><<<dim3(157,1), 256, 0, stream>>>(
      h,nullptr,nullptr,nullptr,nullptr,nullptr, WpT, bp, nullptr,
      nullptr, nullptr, nullptr, nullptr, nullptr, out);
}

// Round 5
// 1145.982 us; speedup vs baseline: 2.7669x; 1.0600x over previous
//
#include <hip/hip_runtime.h>

#define T_STEPS 10
#define NN 10000
#define EE 320000
#define CC 128
#define NC (NN*CC)
#define BHIST 32
#define EPB (EE/BHIST)   // 10000 edges per hist/place block

typedef unsigned short u16;
typedef unsigned int u32;
typedef __attribute__((ext_vector_type(8))) short bf16x8;
typedef __attribute__((ext_vector_type(4))) float f32x4;

__device__ __forceinline__ float sigmoidf_(float x){ return 1.f/(1.f+__expf(-x)); }
__device__ __forceinline__ float tanhf_(float x){
  x = fminf(15.f, fmaxf(-15.f, x));
  float e = __expf(2.f*x);
  return (e-1.f)/(e+1.f);
}
__device__ __forceinline__ u16 f2bf(float f){
  u32 u = __float_as_uint(f);
  u32 r = u + 0x7fffu + ((u>>16)&1u);
  return (u16)(r>>16);
}
__device__ __forceinline__ float bf2f(u16 s){
  return __uint_as_float(((u32)s)<<16);
}
__device__ __forceinline__ void gload16(const void* g, void* l){
  __builtin_amdgcn_global_load_lds(
    (const __attribute__((address_space(1))) void*)g,
    (__attribute__((address_space(3))) void*)l, 16, 0, 0);
}

// ---------------- prep: transposed bf16 effective weights + biases + h0 -----
__global__ __launch_bounds__(256) void prep_kernel(
    const float* __restrict__ Wxz, const float* __restrict__ Whz,
    const float* __restrict__ Wxr, const float* __restrict__ Whr,
    const float* __restrict__ Wxh, const float* __restrict__ Whh,
    const float* __restrict__ bxz, const float* __restrict__ bhz,
    const float* __restrict__ bxr, const float* __restrict__ bhr,
    const float* __restrict__ bxh, const float* __restrict__ bhh,
    const float* __restrict__ Wp,
    u16* __restrict__ WbigT, u16* __restrict__ WrT, u16* __restrict__ WpT,
    float* __restrict__ bz, float* __restrict__ br, float* __restrict__ bht,
    u16* __restrict__ h)
{
  int idx = blockIdx.x*256 + threadIdx.x;
  if (idx < NC) h[idx] = 0;
  if (idx < 384*768) {
    int c = idx / 768, k = idx - c*768;
    int gate = c >> 7, cc = c & 127;
    int hside = (k >= 384);
    int kk = hside ? k - 384 : k;
    int blk = kk >> 7, row = kk & 127;
    const float* W = nullptr;
    if (!hside) W = (gate==0) ? Wxz : (gate==1) ? Wxr : Wxh;
    else if (gate==0) W = Whz; else if (gate==1) W = Whr;
    float v = 0.f;
    if (W) {
      int base = row*CC + cc;
      float w0 = W[base], w1 = W[CC*CC + base], w2 = W[2*CC*CC + base];
      v = (blk==0) ? (w0 - w2) : (blk==1) ? w1 : (2.f*w2);
    }
    WbigT[idx] = f2bf(v);
  }
  if (idx < 128*384) {
    int c = idx / 384, k = idx - c*384;
    int blk = k >> 7, row = k & 127;
    int base = row*CC + c;
    float w0 = Whh[base], w1 = Whh[CC*CC+base], w2 = Whh[2*CC*CC+base];
    WrT[idx] = f2bf((blk==0) ? (w0-w2) : (blk==1) ? w1 : (2.f*w2));
  }
  if (idx < 64*128) {
    int c = idx >> 7, k = idx & 127;
    WpT[idx] = f2bf(Wp[k*64 + c]);
  }
  if (idx < CC) {
    bz[idx]  = bxz[idx] + bhz[idx];
    br[idx]  = bxr[idx] + bhr[idx];
    bht[idx] = bxh[idx] + bhh[idx];
  }
}

// fp32 -> bf16, 4 elems/thread; n4 = number of float4 chunks
__global__ __launch_bounds__(256) void xconv_kernel(const float* __restrict__ x, u16* __restrict__ xb, int n4){
  int i = blockIdx.x*256 + threadIdx.x;
  if (i >= n4) return;
  long long o = (long long)i*4;
  float4 v = *(const float4*)(x + o);
  u32 u0 = (u32)f2bf(v.x) | ((u32)f2bf(v.y)<<16);
  u32 u1 = (u32)f2bf(v.z) | ((u32)f2bf(v.w)<<16);
  uint2 r; r.x=u0; r.y=u1;
  *(uint2*)(xb + o) = r;
}

// ---------------- graph build: packed LDS histograms, zero global atomics --
// hist: block (b,t) bins its EPB edges into ONE u32 LDS array:
//   low16 = deg over src, high16 = cnt over dst (max degree ~70 << 65536).
__global__ __launch_bounds__(256) void hist_kernel(const int* __restrict__ edges,
                                                   u32* __restrict__ histP){
  __shared__ u32 hist[NN];   // 40 KB -> 4 blocks/CU
  int t = blockIdx.y, b = blockIdx.x, tid = threadIdx.x;
  for (int i = tid; i < NN; i += 256) hist[i] = 0;
  __syncthreads();
  const int* src = edges + (size_t)t*2*EE;
  const int* dst = src + EE;
  int e1 = b*EPB + EPB;
  #pragma unroll 4
  for (int e = b*EPB + tid; e < e1; e += 256){
    int s = src[e], d = dst[e];
    if (s != d){
      atomicAdd(&hist[s], 1u);         // ds_add, LDS-local
      atomicAdd(&hist[d], 1u << 16);
    }
  }
  __syncthreads();
  u32* hp = histP + ((size_t)t*BHIST + b)*NN;
  for (int i = tid; i < NN; i += 256) hp[i] = hist[i];
}

// reduce: per (t,d): deg total -> dinv; cnt total -> cnt_all; rewrite each
// partial's high16 with the exclusive prefix of cnt (fits 16b: <= degree).
__global__ __launch_bounds__(256) void reduce_kernel(u32* __restrict__ histP,
                                                     int* __restrict__ cnt_all, float* __restrict__ dinv_all){
  int t = blockIdx.y;
  int d = blockIdx.x*256 + threadIdx.x;
  if (d >= NN) return;
  size_t base = (size_t)t*BHIST*NN + d;
  u32 run = 0, degs = 0;
  #pragma unroll
  for (int b = 0; b < BHIST; ++b){
    size_t ix = base + (size_t)b*NN;
    u32 v = histP[ix];
    histP[ix] = (v & 0xffffu) | (run << 16);
    run += v >> 16;
    degs += v & 0xffffu;
  }
  cnt_all[t*NN + d] = (int)run;
  dinv_all[t*NN + d] = degs > 0 ? rsqrtf((float)degs) : 0.f;
}

// one block per timestep; shfl-based scan of cnt[NN] -> rowptr[NN+1]
__global__ __launch_bounds__(1024) void scan_kernel(const int* __restrict__ cnt_all,
                                                    int* __restrict__ rowptr_all){
  int t = blockIdx.x;
  const int* cnt = cnt_all + (size_t)t*NN;
  int* rowptr = rowptr_all + (size_t)t*(NN+1);
  __shared__ int wsum[16];
  __shared__ int carry_s;
  int tid = threadIdx.x, lane = tid & 63, wvi = tid >> 6;
  if (tid==0) carry_s = 0;
  __syncthreads();
  for (int base=0; base<NN; base+=1024){
    int i = base+tid;
    int v = (i<NN) ? cnt[i] : 0;
    int s = v;
    #pragma unroll
    for (int off=1; off<64; off<<=1){
      int u = __shfl_up(s, off, 64);
      if (lane>=off) s += u;
    }
    if (lane==63) wsum[wvi] = s;
    __syncthreads();
    if (wvi==0 && lane<16){
      int ws = wsum[lane];
      #pragma unroll
      for (int off=1; off<16; off<<=1){
        int u = __shfl_up(ws, off, 64);
        if (lane>=off) ws += u;
      }
      wsum[lane] = ws;
    }
    __syncthreads();
    int incl = s + (wvi ? wsum[wvi-1] : 0) + carry_s;
    if (i<NN){
      rowptr[i] = incl - v;
      if (i==NN-1) rowptr[NN] = incl;
    }
    __syncthreads();
    if (tid==1023) carry_s = incl;
    __syncthreads();
  }
}

// place: counting-sort scatter. Block (b,t) seeds LDS counters with
// rowptr[d] + its exclusive base (partial high16), ranks edges via LDS
// atomics, writes colA directly.
__global__ __launch_bounds__(256) void place_kernel(const int* __restrict__ edges,
                                                    const int* __restrict__ rowptr_all,
                                                    const u32* __restrict__ histP,
                                                    int* __restrict__ colA_all){
  __shared__ int slot[NN];     // 40 KB
  int t = blockIdx.y, b = blockIdx.x, tid = threadIdx.x;
  const int* rowptr = rowptr_all + (size_t)t*(NN+1);
  const u32* hp = histP + ((size_t)t*BHIST + b)*NN;
  for (int i = tid; i < NN; i += 256) slot[i] = rowptr[i] + (int)(hp[i] >> 16);
  __syncthreads();
  const int* src = edges + (size_t)t*2*EE;
  const int* dst = src + EE;
  int* colA = colA_all + (size_t)t*EE;
  int e1 = b*EPB + EPB;
  #pragma unroll 4
  for (int e = b*EPB + tid; e < e1; e += 256){
    int s = src[e], d = dst[e];
    if (s != d){
      int pos = atomicAdd(&slot[d], 1);   // LDS atomic, returns rank
      colA[pos] = s;
    }
  }
}

// ---------------- CSR SpMM bf16: out[d,:] = sum -dinv[d]dinv[s] in[s,:] ----
// single-input variant (hr path)
__global__ __launch_bounds__(256) void spmm_kernel(const int* __restrict__ rowptr, const int* __restrict__ colA,
                                                   const float* __restrict__ dinv,
                                                   const u16* __restrict__ in, u16* __restrict__ out){
  int wave = threadIdx.x >> 6, lane = threadIdx.x & 63;
  int row = blockIdx.x*4 + wave;
  if (row >= NN) return;
  int k0 = rowptr[row], k1 = rowptr[row+1];
  float wrow = -dinv[row];
  float ax=0.f, ay=0.f;
  #pragma unroll 4
  for (int k=k0;k<k1;k++){
    int s = colA[k];
    float w = wrow * dinv[s];
    u32 u = *(const u32*)(in + (size_t)s*CC + lane*2);
    ax = fmaf(w, __uint_as_float(u<<16), ax);
    ay = fmaf(w, __uint_as_float(u & 0xffff0000u), ay);
  }
  u32 res = (u32)f2bf(ax) | ((u32)f2bf(ay)<<16);
  *(u32*)(out + (size_t)row*CC + lane*2) = res;
}

// dual-input variant, XCD-pinned: blocks with (bid&7)<4 process input0 on
// XCDs 0-3, others input1 on XCDs 4-7 -> each XCD's L2 holds one 2.5MB matrix.
__global__ __launch_bounds__(256) void spmm2_kernel(const int* __restrict__ rowptr, const int* __restrict__ colA,
                                                    const float* __restrict__ dinv,
                                                    const u16* __restrict__ in0, u16* __restrict__ out0,
                                                    const u16* __restrict__ in1, u16* __restrict__ out1){
  int wave = threadIdx.x >> 6, lane = threadIdx.x & 63;
  int bid = blockIdx.x;
  int xcd = bid & 7;
  int inp = xcd >> 2;
  int wb  = (bid >> 3)*4 + (xcd & 3);   // [0, NN/4)
  int row = wb*4 + wave;
  const u16* __restrict__ in = inp ? in1 : in0;
  u16* __restrict__ out = inp ? out1 : out0;
  if (row >= NN) return;
  int k0 = rowptr[row], k1 = rowptr[row+1];
  float wrow = -dinv[row];
  float ax=0.f, ay=0.f;
  #pragma unroll 4
  for (int k=k0;k<k1;k++){
    int s = colA[k];
    float w = wrow * dinv[s];
    u32 u = *(const u32*)(in + (size_t)s*CC + lane*2);
    ax = fmaf(w, __uint_as_float(u<<16), ax);
    ay = fmaf(w, __uint_as_float(u & 0xffff0000u), ay);
  }
  u32 res = (u32)f2bf(ax) | ((u32)f2bf(ay)<<16);
  *(u32*)(out + (size_t)row*CC + lane*2) = res;
}

// ---------------- bf16 MFMA GEMM: C[m, n] over segmented K -----------------
// BM=BN=64, BK=64, 4 waves, each wave a 32x32 quadrant (2x2 frags).
// LDS tiles [64 rows][8 x 16B chunks], XOR swizzle chunk^=(row&7), staged by
// global_load_lds with pre-swizzled SOURCE (both-sides rule #21).
template<int NSEG, int KDIM, int EPI>
__global__ __launch_bounds__(256) void mgemm_kernel(
    const u16* __restrict__ A0, const u16* __restrict__ A1, const u16* __restrict__ A2,
    const u16* __restrict__ A3, const u16* __restrict__ A4, const u16* __restrict__ A5,
    const u16* __restrict__ Bt,
    const float* __restrict__ bias0, const float* __restrict__ bias1,
    const u16* __restrict__ hbuf,
    float* __restrict__ zbuf, float* __restrict__ chx,
    u16* __restrict__ hr_out, u16* __restrict__ h_out,
    float* __restrict__ out_f)
{
  __shared__ __align__(16) u16 As[64*64];
  __shared__ __align__(16) u16 Bs[64*64];
  const u16* segs[6] = {A0,A1,A2,A3,A4,A5};
  int tid = threadIdx.x, lane = tid & 63, wvi = tid >> 6;
  int m0 = blockIdx.x*64, n0 = blockIdx.y*64;
  int wr = wvi >> 1, wc = wvi & 1;

  f32x4 acc[2][2] = {};

  int c0 = wvi*64 + lane;
  int r0 = c0 >> 3, cc0 = c0 & 7;
  int scw = cc0 ^ (r0 & 7);
  int grow0 = m0 + r0;      if (grow0 > NN-1) grow0 = NN-1;
  int grow1 = m0 + r0 + 32; if (grow1 > NN-1) grow1 = NN-1;
  int nrow0 = n0 + r0, nrow1 = nrow0 + 32;
  u16* ldsA0 = (u16*)As + (size_t)wvi*64*8;
  u16* ldsA1 = ldsA0 + 256*8;
  u16* ldsB0 = (u16*)Bs + (size_t)wvi*64*8;
  u16* ldsB1 = ldsB0 + 256*8;

  int rl = lane & 15, rg = lane >> 4, sw = rl & 7;
  int rowa0 = wr*32 + rl, rowb0 = wc*32 + rl;
  int offA[2][2], offB[2][2];
  #pragma unroll
  for (int mf=0; mf<2; ++mf)
    #pragma unroll
    for (int ks=0; ks<2; ++ks){
      offA[mf][ks] = (rowa0 + mf*16)*128 + ((((ks<<2)+rg) ^ sw)<<4);
      offB[mf][ks] = (rowb0 + mf*16)*128 + ((((ks<<2)+rg) ^ sw)<<4);
    }

  for (int kt=0; kt<NSEG*2; ++kt){
    const u16* __restrict__ Aseg = segs[kt>>1];
    int ko = (kt&1)*64;
    __syncthreads();
    gload16(Aseg + (size_t)grow0*CC + ko + scw*8, ldsA0);
    gload16(Aseg + (size_t)grow1*CC + ko + scw*8, ldsA1);
    gload16(Bt + (size_t)nrow0*KDIM + kt*64 + scw*8, ldsB0);
    gload16(Bt + (size_t)nrow1*KDIM + kt*64 + scw*8, ldsB1);
    __syncthreads();
    #pragma unroll
    for (int ks=0; ks<2; ++ks){
      bf16x8 a0 = *(const bf16x8*)((const char*)As + offA[0][ks]);
      bf16x8 a1 = *(const bf16x8*)((const char*)As + offA[1][ks]);
      bf16x8 b0 = *(const bf16x8*)((const char*)Bs + offB[0][ks]);
      bf16x8 b1 = *(const bf16x8*)((const char*)Bs + offB[1][ks]);
      acc[0][0] = __builtin_amdgcn_mfma_f32_16x16x32_bf16(a0, b0, acc[0][0], 0,0,0);
      acc[0][1] = __builtin_amdgcn_mfma_f32_16x16x32_bf16(a0, b1, acc[0][1], 0,0,0);
      acc[1][0] = __builtin_amdgcn_mfma_f32_16x16x32_bf16(a1, b0, acc[1][0], 0,0,0);
      acc[1][1] = __builtin_amdgcn_mfma_f32_16x16x32_bf16(a1, b1, acc[1][1], 0,0,0);
    }
  }

  // epilogue: C/D layout col=lane&15, row=(lane>>4)*4+reg  [guide m89]
  #pragma unroll
  for (int mf=0; mf<2; ++mf){
    #pragma unroll
    for (int nf=0; nf<2; ++nf){
      #pragma unroll
      for (int r=0; r<4; ++r){
        int grow = m0 + wr*32 + mf*16 + rg*4 + r;
        if (grow >= NN) continue;
        int gcol = n0 + wc*32 + nf*16 + rl;
        float v = acc[mf][nf][r];
        if (EPI==0){
          out_f[(size_t)grow*64 + gcol] = v + bias0[gcol];
        } else if (EPI==1){
          int gate = gcol >> 7, c = gcol & 127;
          size_t idx = (size_t)grow*CC + c;
          if (gate==0)      zbuf[idx] = sigmoidf_(v + bias0[c]);
          else if (gate==1){
            float rr = sigmoidf_(v + bias1[c]);
            hr_out[idx] = f2bf(rr * bf2f(hbuf[idx]));
          } else            chx[idx] = v;
        } else {
          size_t idx = (size_t)grow*CC + gcol;
          float pre = v + chx[idx] + bias0[gcol];
          float ht = tanhf_(pre);
          float zz = zbuf[idx];
          float hv = bf2f(hbuf[idx]);
          h_out[idx] = f2bf(fmaf(zz, hv - ht, ht));
        }
      }
    }
  }
}

extern "C" void kernel_launch(void* const* d_in, const int* in_sizes, int n_in,
                              void* d_out, int out_size, void* d_ws, size_t ws_size,
                              hipStream_t stream)
{
  (void)in_sizes; (void)n_in; (void)out_size;
  const float* feat = (const float*)d_in[0];
  const int*   edges = (const int*)d_in[1];
  const float* Wxz=(const float*)d_in[2];  const float* bxz=(const float*)d_in[3];
  const float* Whz=(const float*)d_in[4];  const float* bhz=(const float*)d_in[5];
  const float* Wxr=(const float*)d_in[6];  const float* bxr=(const float*)d_in[7];
  const float* Whr=(const float*)d_in[8];  const float* bhr=(const float*)d_in[9];
  const float* Wxh=(const float*)d_in[10]; const float* bxh=(const float*)d_in[11];
  const float* Whh=(const float*)d_in[12]; const float* bhh=(const float*)d_in[13];
  const float* Wp =(const float*)d_in[14]; const float* bp =(const float*)d_in[15];
  float* out = (float*)d_out;

  const bool full_xb = ws_size >= (size_t)100*1024*1024;

  char* p = (char*)d_ws;
  auto alloc = [&](size_t bytes)->char* {
    char* r = p; p += (bytes + 255) & ~(size_t)255; return r;
  };
  u16* xb   = (u16*)alloc((full_xb ? (size_t)T_STEPS : 1)*(size_t)NC*2);
  u16* h    = (u16*)alloc((size_t)NC*2);
  u16* a1x  = (u16*)alloc((size_t)NC*2);
  u16* a2x  = (u16*)alloc((size_t)NC*2);
  u16* a1h  = (u16*)alloc((size_t)NC*2);
  u16* a2h  = (u16*)alloc((size_t)NC*2);
  u16* hr   = (u16*)alloc((size_t)NC*2);
  float* zbuf = (float*)alloc((size_t)NC*4);
  float* chx  = (float*)alloc((size_t)NC*4);
  u16* WbigT = (u16*)alloc(384*768*2);
  u16* WrT   = (u16*)alloc(128*384*2);
  u16* WpT   = (u16*)alloc(64*128*2);
  float* bz  = (float*)alloc(CC*4);
  float* br  = (float*)alloc(CC*4);
  float* bht = (float*)alloc(CC*4);
  float* dinv_all = (float*)alloc((size_t)T_STEPS*NN*4);
  int* cnt_all    = (int*)alloc((size_t)T_STEPS*NN*4);
  int* rowptr_all = (int*)alloc((size_t)T_STEPS*(NN+1)*4);
  int* colA_all   = (int*)alloc((size_t)T_STEPS*EE*4);
  // packed hist partials (BHIST*T*NN u32 = 12.8MB) alias hr+zbuf+chx
  // (contiguous 2.56+5.12+5.12 MB, all 256B-aligned sizes; dead until the
  // recurrence loop first writes them — build completes before step 0)
  u32* histP = (u32*)hr;
  // hr-path agg buffers alias the x-path ones (dead after GEMM1)
  u16* a1r = a1x;
  u16* a2r = a2x;

  prep_kernel<<<NC/256, 256, 0, stream>>>(Wxz,Whz,Wxr,Whr,Wxh,Whh,
                                          bxz,bhz,bxr,bhr,bxh,bhh, Wp,
                                          WbigT, WrT, WpT, bz, br, bht, h);
  if (full_xb)
    xconv_kernel<<<(T_STEPS*NC/4 + 255)/256, 256, 0, stream>>>(feat, xb, T_STEPS*NC/4);

  hist_kernel<<<dim3(BHIST, T_STEPS), 256, 0, stream>>>(edges, histP);
  reduce_kernel<<<dim3((NN+255)/256, T_STEPS), 256, 0, stream>>>(histP, cnt_all, dinv_all);
  scan_kernel<<<T_STEPS, 1024, 0, stream>>>(cnt_all, rowptr_all);
  place_kernel<<<dim3(BHIST, T_STEPS), 256, 0, stream>>>(edges, rowptr_all, histP, colA_all);

  for (int t=0; t<T_STEPS; ++t){
    const int*   rowptr = rowptr_all + (size_t)t*(NN+1);
    const int*   colA   = colA_all + (size_t)t*EE;
    const float* dinv   = dinv_all + (size_t)t*NN;
    const u16*   x;
    if (full_xb){
      x = xb + (size_t)t*NC;
    } else {
      xconv_kernel<<<(NC/4 + 255)/256, 256, 0, stream>>>(feat + (size_t)t*NC, xb, NC/4);
      x = xb;
    }

    spmm2_kernel<<<dim3(2*(NN/4)), 256, 0, stream>>>(rowptr,colA,dinv, x,a1x, h,a1h);
    spmm2_kernel<<<dim3(2*(NN/4)), 256, 0, stream>>>(rowptr,colA,dinv, a1x,a2x, a1h,a2h);

    mgemm_kernel<6,768,1><<<dim3(157,6), 256, 0, stream>>>(
        x,a1x,a2x,h,a1h,a2h, WbigT, bz, br, h, zbuf, chx, hr, nullptr, nullptr);

    spmm_kernel<<<dim3(NN/4), 256, 0, stream>>>(rowptr,colA,dinv, hr,a1r);
    spmm_kernel<<<dim3(NN/4), 256, 0, stream>>>(rowptr,colA,dinv, a1r,a2r);

    mgemm_kernel<3,384,2><<<dim3(157,2), 256, 0, stream>>>(
        hr,a1r,a2r,nullptr,nullptr,nullptr, WrT, bht, nullptr, h, zbuf, chx,
        nullptr, h, nullptr);
  }

  mgemm_kernel<1,128,0><<<dim3(157,1), 256, 0, stream>>>(
      h,nullptr,nullptr,nullptr,nullptr,nullptr, WpT, bp, nullptr,
      nullptr, nullptr, nullptr, nullptr, nullptr, out);
}